// Round 5
// baseline (855.138 us; speedup 1.0000x reference)
//
#include <hip/hip_runtime.h>
#include <cmath>

static constexpr int Bn = 128;
static constexpr int Nn = 256;
static constexpr int META_PB = 131072;   // per-batch metadata bytes (uint8)

// ---------------------------------------------------------------------------
// Kernel 1: z = logits - log(-log(clip(u))), zero arb, init score matrix
// M[b][i][j] (stride 256) with diag & column-0 = -inf.
// ---------------------------------------------------------------------------
template <typename T>
__global__ __launch_bounds__(256) void zinit_kernel(
    const float* __restrict__ logits,
    const float* __restrict__ u,
    float* __restrict__ zout,
    float* __restrict__ arb,
    T* __restrict__ M)
{
    int idx = blockIdx.x * blockDim.x + threadIdx.x;   // < Bn*Nn*Nn
    int j = idx & (Nn - 1);
    int i = (idx >> 8) & (Nn - 1);
    const float EPS = 1.1920928955078125e-07f;         // float32 eps
    float uv = u[idx];
    uv = fminf(fmaxf(uv, EPS), 1.0f - EPS);
    float z = logits[idx] - logf(-logf(uv));
    zout[idx] = z;
    arb[idx] = 0.0f;
    M[idx] = (i == j || j == 0) ? (T)(-INFINITY) : (T)z;
}

// select a[v] from 4-segment register-resident array (64 lanes x 4 segs)
__device__ __forceinline__ int sel4(int v, int a0, int a1, int a2, int a3) {
    int x0 = __shfl(a0, v & 63);
    int x1 = __shfl(a1, v & 63);
    int x2 = __shfl(a2, v & 63);
    int x3 = __shfl(a3, v & 63);
    int s = v >> 6;
    return s == 0 ? x0 : (s == 1 ? x1 : (s == 2 ? x2 : x3));
}

// ---------------------------------------------------------------------------
// Kernel 2: per-batch Chu-Liu/Edmonds, 256 threads/block, in-place supernode
// contraction + incremental argmax. Cycle detection runs entirely in wave-0
// registers (shfl-based pointer doubling); 6 barriers per level.
// ---------------------------------------------------------------------------
template <typename T>
__global__ __launch_bounds__(256) void edmonds_kernel(
    const int* __restrict__ lengths,
    const float* __restrict__ zout,
    T* __restrict__ Mg,
    unsigned char* __restrict__ metag,
    float* __restrict__ arb,
    float* __restrict__ stats)
{
    const int b = blockIdx.x;
    const int t = threadIdx.x;
    const int lane = t & 63, wv = t >> 6;
    T* M = Mg + (size_t)b * (Nn * Nn);
    unsigned char* meta = metag + (size_t)b * META_PB;
    const float* zb = zout + (size_t)b * (Nn * Nn);

    __shared__ unsigned short act[256];   // compact index -> original slot
    __shared__ unsigned short h[256];     // compact heads
    __shared__ unsigned short h2[256];    // unwind ping-pong
    __shared__ unsigned short inv_[256];  // old compact -> new compact
    __shared__ unsigned short cyc_c[256];
    __shared__ unsigned short non_c[256];
    __shared__ unsigned short cslot_s[256];
    __shared__ unsigned short resc[256];
    __shared__ unsigned short lev_n[256], lev_c[256];
    __shared__ int lev_off[256];
    __shared__ unsigned char in_cyc[256];
    __shared__ T hval[256];               // per-column current max value
    __shared__ T chs[256];
    __shared__ double red[256];
    __shared__ int wcnt[4];
    __shared__ int sh_clen, sh_cnt, sh_wslot;

    const int L = lengths[b];

    act[t] = (unsigned short)t;
    in_cyc[t] = 0;
    // ---- initial full column argmax (first-max, coalesced across t) ----
    if (t < L) {
        T best = -INFINITY; int bi = 0;
        const T* col = M + t;
        for (int i = 0; i < L; ++i) {
            T v = col[i * Nn];
            if (v > best) { best = v; bi = i; }
        }
        h[t] = (t == 0) ? (unsigned short)0 : (unsigned short)bi;
        hval[t] = best;
    } else {
        h[t] = 0;
        hval[t] = (T)0;
    }
    __syncthreads();

    int Lc = L, depth = 0, moff = 0;

    while (true) {
        // ---- S1: wave-0 register cycle detection ----
        if (wv == 0) {
            int h0 = h[lane], h1 = h[64 | lane], h2r = h[128 | lane], h3 = h[192 | lane];
            int p0 = h0, p1 = h1, p2 = h2r, p3 = h3;
            const int rounds = 32 - __clz(Lc - 1);    // ceil(log2(Lc)), Lc>=2
            for (int r = 0; r < rounds; ++r) {
                int n0 = sel4(p0, p0, p1, p2, p3);
                int n1 = sel4(p1, p0, p1, p2, p3);
                int n2 = sel4(p2, p0, p1, p2, p3);
                int n3 = sel4(p3, p0, p1, p2, p3);
                p0 = n0; p1 = n1; p2 = n2; p3 = n3;
            }
            // min v>=1 whose chain terminates on a non-root cycle
            unsigned cand = 0xFFFFu;
            if (lane >= 1 && lane < Lc && p0 != 0) cand = (unsigned)lane;
            { int i1 = 64 | lane;  if (i1 < Lc && p1 != 0) cand = min(cand, (unsigned)i1); }
            { int i2 = 128 | lane; if (i2 < Lc && p2 != 0) cand = min(cand, (unsigned)i2); }
            { int i3 = 192 | lane; if (i3 < Lc && p3 != 0) cand = min(cand, (unsigned)i3); }
            for (int m = 1; m < 64; m <<= 1)
                cand = min(cand, (unsigned)__shfl((int)cand, (lane ^ m) & 63));
            if (cand == 0xFFFFu) {
                if (lane == 0) sh_clen = 0;
            } else {
                const int w = sel4((int)cand, p0, p1, p2, p3);  // a node ON the cycle
                int cl = 0, v = w;
                do {
                    if (lane == 0) { cyc_c[cl] = (unsigned short)v; in_cyc[v] = 1; }
                    ++cl;
                    v = sel4(v, h0, h1, h2r, h3);
                } while (v != w);
                if (lane == 0) {
                    sh_clen = cl;
                    sh_wslot = act[w];
                    sh_cnt = 0;
                }
            }
        }
        __syncthreads();                              // B1
        const int clen = sh_clen;
        if (clen == 0) break;                         // h[] is the solution
        const int n = Lc - clen;
        const int wslot = sh_wslot;

        // ---- S2: ballot counts for order-preserving compaction ----
        const bool fl = (t < Lc) && !in_cyc[t];
        unsigned long long mask = __ballot(fl);
        if (lane == 0) wcnt[wv] = __popcll(mask);
        __syncthreads();                              // B2

        // ---- S3: non list, inverse map, cycle slot/score caches ----
        if (fl) {
            int base = 0;
            for (int k = 0; k < wv; ++k) base += wcnt[k];
            int pos = base + __popcll(mask & ((1ull << lane) - 1ull));
            non_c[pos] = (unsigned short)t;
            inv_[t] = (unsigned short)pos;
        }
        if (t < clen) {
            const int cc = cyc_c[t];
            chs[t] = hval[cc];                        // = M[heads[cyc]][cyc]
            cslot_s[t] = act[cc];
        }
        __syncthreads();                              // B3

        // ---- S4: into/outo maxes, meta push, supernode row/col, capture ----
        T vin_r = (T)0, vout_r = (T)0;
        unsigned char argin_r = 0, argout_r = 0;
        int slot_r = 0;
        if (t < n) {
            slot_r = act[non_c[t]];
            T bv = -INFINITY; int bi = 0;
            T bo = -INFINITY; int bj = 0;
            for (int c = 0; c < clen; ++c) {
                const int cs = cslot_s[c];
                T vi = M[slot_r * Nn + cs] - chs[c];
                T vo = M[cs * Nn + slot_r];
                if (vi > bv) { bv = vi; bi = c; }
                if (vo > bo) { bo = vo; bj = c; }
            }
            vin_r = bv; argin_r = (unsigned char)bi;
            vout_r = bo; argout_r = (unsigned char)bj;
        }
        unsigned char* mp = meta + moff;
        if (t < n) {
            mp[t] = (unsigned char)non_c[t];
            mp[n + t] = argin_r;
            mp[2 * n + t] = argout_r;
            M[slot_r * Nn + wslot] = vin_r;           // new supernode column
            M[wslot * Nn + slot_r] = vout_r;          // new supernode row
        }
        if (t < clen) {
            mp[3 * n + t] = (unsigned char)cyc_c[t];
            mp[3 * n + clen + t] = (unsigned char)h[cyc_c[t]];
        }
        if (t == 0) {
            M[wslot * Nn + wslot] = (T)(-INFINITY);
            lev_n[depth] = (unsigned short)n;
            lev_c[depth] = (unsigned short)clen;
            lev_off[depth] = moff;
        }
        unsigned short myact = 0, myh = 0; T myhval = (T)0; bool need = false;
        if (t < n) {
            const int oc = non_c[t];
            myact = act[oc];
            const int ho = h[oc];
            need = (in_cyc[ho] != 0);
            if (!need) { myh = inv_[ho]; myhval = hval[oc]; }
        }
        __syncthreads();                              // B4

        // ---- S5: remap to new compact space, clear in_cyc for next level ----
        if (t < n) {
            act[t] = myact;
            if (!need) { h[t] = myh; hval[t] = myhval; }
            else { int kk = atomicAdd(&sh_cnt, 1); resc[kk] = (unsigned short)t; }
        }
        if (t == 0) {
            act[n] = (unsigned short)wslot;
            int kk = atomicAdd(&sh_cnt, 1); resc[kk] = (unsigned short)n;
            h[0] = 0;
        }
        in_cyc[t] = 0;
        __syncthreads();                              // B5
        moff += 3 * n + 2 * clen;
        ++depth;
        Lc = n + 1;

        // ---- S6: rescan invalidated columns (parallel, first-max) ----
        const int nr = sh_cnt;
        if (t < nr) {
            const int jc = resc[t];
            const int cslot = act[jc];
            T best = -INFINITY; int bi = 0;
            for (int i = 0; i < Lc; ++i) {
                T v = M[(int)act[i] * Nn + cslot];
                if (v > best) { best = v; bi = i; }
            }
            h[jc] = (unsigned short)bi;
            hval[jc] = best;
        }
        __syncthreads();                              // B6
    }

    // ---- unwind ----
    unsigned short* hcur = h;
    unsigned short* hnew = h2;
    for (int lvl = depth - 1; lvl >= 0; --lvl) {
        const int n = lev_n[lvl];
        const int c = lev_c[lvl];
        const unsigned char* mp = meta + lev_off[lvl];
        const unsigned char* pnon    = mp;
        const unsigned char* pargin  = mp + n;
        const unsigned char* pargout = mp + 2 * n;
        const unsigned char* pcyc    = mp + 3 * n;
        const unsigned char* phcyc   = mp + 3 * n + c;
        if (t < n) {
            const int x = hcur[t];
            hnew[pnon[t]] = (x == n) ? (unsigned short)pcyc[pargout[t]]
                                     : (unsigned short)pnon[x];
        }
        if (t < c) hnew[pcyc[t]] = phcyc[t];
        __syncthreads();
        if (t == 0) {
            const int hc = hcur[n];
            hnew[pcyc[pargin[hc]]] = pnon[hc];
            hnew[0] = 0;
        }
        __syncthreads();
        unsigned short* tmp = hcur; hcur = hnew; hnew = tmp;
    }

    // ---- emit arb (ones) and stats ----
    double acc = 0.0;
    if (t >= 1 && t < L) {
        const int hd = hcur[t];
        arb[(size_t)b * (Nn * Nn) + hd * Nn + t] = 1.0f;
        acc = (double)zb[hd * Nn + t];
    }
    red[t] = acc;
    __syncthreads();
    for (int s = 128; s > 0; s >>= 1) {
        if (t < s) red[t] += red[t + s];
        __syncthreads();
    }
    if (t == 0) stats[b] = (float)red[0];
}

// ---------------------------------------------------------------------------
extern "C" void kernel_launch(void* const* d_in, const int* in_sizes, int n_in,
                              void* d_out, int out_size, void* d_ws, size_t ws_size,
                              hipStream_t stream)
{
    const float* logits  = (const float*)d_in[0];
    const float* u       = (const float*)d_in[1];
    const int*   lengths = (const int*)d_in[2];

    float* out   = (float*)d_out;
    float* arb   = out;                                  // Bn*Nn*Nn
    float* stats = out + (size_t)Bn * Nn * Nn;           // Bn
    float* zout  = stats + Bn;                           // Bn*Nn*Nn

    const int total = Bn * Nn * Nn;
    const int zblocks = total / 256;

    const size_t needD = (size_t)Bn * Nn * Nn * sizeof(double) + (size_t)Bn * META_PB;

    if (ws_size >= needD) {
        double* M = (double*)d_ws;
        unsigned char* meta = (unsigned char*)d_ws + (size_t)Bn * Nn * Nn * sizeof(double);
        zinit_kernel<double><<<zblocks, 256, 0, stream>>>(logits, u, zout, arb, M);
        edmonds_kernel<double><<<Bn, 256, 0, stream>>>(lengths, zout, M, meta, arb, stats);
    } else {
        // fallback: f32 score matrices (tiny risk of ulp-level argmax flips)
        float* M = (float*)d_ws;
        unsigned char* meta = (unsigned char*)d_ws + (size_t)Bn * Nn * Nn * sizeof(float);
        zinit_kernel<float><<<zblocks, 256, 0, stream>>>(logits, u, zout, arb, M);
        edmonds_kernel<float><<<Bn, 256, 0, stream>>>(lengths, zout, M, meta, arb, stats);
    }
}